// Round 12
// baseline (110.227 us; speedup 1.0000x reference)
//
#include <hip/hip_runtime.h>
#include <hip/hip_bf16.h>

#define N_NODES 1024
#define B_SZ 64
#define F_IN 10
#define DIM 64
#define TOPK 20
#define BN_TOT (B_SZ * N_NODES)   // 65536

#define GT_BLKS 1024              // one row per block
#define HS_BLKS 4096              // hscal, 16 nodes/block
#define K1_BLKS (GT_BLKS + HS_BLKS + 1)

// ---- K1: [cos-row + exact top-20] || [hscal] || [bnp fold], all independent ----
__global__ __launch_bounds__(256, 2) void k_build(
    const float* __restrict__ data, const float* __restrict__ emb,
    const float* __restrict__ W_lin,
    const float* __restrict__ att_i, const float* __restrict__ att_j,
    const float* __restrict__ att_em_i, const float* __restrict__ att_em_j,
    const float* __restrict__ gnn_bias,
    const float* __restrict__ g1, const float* __restrict__ b1,
    const float* __restrict__ m1, const float* __restrict__ v1,
    const float* __restrict__ g2, const float* __restrict__ b2,
    const float* __restrict__ m2, const float* __restrict__ v2,
    __hip_bfloat16* __restrict__ h, float* __restrict__ ddt,
    float* __restrict__ sst, int* __restrict__ tk, float4* __restrict__ bnp) {
    const int bid = blockIdx.x;
    const int t = threadIdx.x;
    const int lane = t & 63, w = t >> 6;

    if (bid < GT_BLKS) {
        // ---- cosine row `bid` vs all 1024 nodes + exact top-20 ----
        __shared__ float cv[4 * TOPK];
        __shared__ int ci[4 * TOPK];
        const int row = bid;
        const int j0 = t * 4;                 // 4 consecutive candidate nodes
        const float* __restrict__ ar = emb + row * DIM;   // uniform -> s_loads

        float asq = 0.f;
#pragma unroll
        for (int d = 0; d < 64; ++d) asq = fmaf(ar[d], ar[d], asq);
        const float rni = rsqrtf(asq);

        float dt[4] = {0.f, 0.f, 0.f, 0.f};
        float ns[4] = {0.f, 0.f, 0.f, 0.f};
#pragma unroll
        for (int lq = 0; lq < 4; ++lq) {
            const int d0 = lq * 16;
            // 16 independent float4 loads (4 rows x 16 floats), all in flight
            float4 P[4][4];
#pragma unroll
            for (int r = 0; r < 4; ++r)
#pragma unroll
                for (int q = 0; q < 4; ++q)
                    P[r][q] = *(const float4*)(emb + (j0 + r) * DIM + d0 + q * 4);
            float a[16];
#pragma unroll
            for (int d = 0; d < 16; ++d) a[d] = ar[d0 + d];
#pragma unroll
            for (int r = 0; r < 4; ++r) {
#pragma unroll
                for (int q = 0; q < 4; ++q) {
                    dt[r] = fmaf(a[q * 4 + 0], P[r][q].x, dt[r]);
                    ns[r] = fmaf(P[r][q].x, P[r][q].x, ns[r]);
                    dt[r] = fmaf(a[q * 4 + 1], P[r][q].y, dt[r]);
                    ns[r] = fmaf(P[r][q].y, P[r][q].y, ns[r]);
                    dt[r] = fmaf(a[q * 4 + 2], P[r][q].z, dt[r]);
                    ns[r] = fmaf(P[r][q].z, P[r][q].z, ns[r]);
                    dt[r] = fmaf(a[q * 4 + 3], P[r][q].w, dt[r]);
                    ns[r] = fmaf(P[r][q].w, P[r][q].w, ns[r]);
                }
            }
        }
        float v0 = dt[0] * rni * rsqrtf(ns[0]);
        float v1 = dt[1] * rni * rsqrtf(ns[1]);
        float v2 = dt[2] * rni * rsqrtf(ns[2]);
        float v3 = dt[3] * rni * rsqrtf(ns[3]);

        // phase 1: per-wave exact top-20 of its 256 cols (static regs only)
        for (int it = 0; it < TOPK; ++it) {
            float bv = v0; int bq = 0;
            if (v1 > bv) { bv = v1; bq = 1; }
            if (v2 > bv) { bv = v2; bq = 2; }
            if (v3 > bv) { bv = v3; bq = 3; }
            int bidx = j0 + bq;
#pragma unroll
            for (int m = 32; m >= 1; m >>= 1) {
                float ov = __shfl_xor(bv, m, 64);
                int oi = __shfl_xor(bidx, m, 64);
                if (ov > bv || (ov == bv && oi < bidx)) { bv = ov; bidx = oi; }
            }
            if (lane == 0) { cv[w * TOPK + it] = bv; ci[w * TOPK + it] = bidx; }
            v0 = (j0 + 0 == bidx) ? -3.0e38f : v0;
            v1 = (j0 + 1 == bidx) ? -3.0e38f : v1;
            v2 = (j0 + 2 == bidx) ? -3.0e38f : v2;
            v3 = (j0 + 3 == bidx) ? -3.0e38f : v3;
        }
        __syncthreads();

        // phase 2: wave 0 merges 80 candidates (2 static regs/lane) -> top-20
        if (w == 0) {
            float m0 = cv[lane];
            int i0 = ci[lane];
            float m1 = -3.0e38f;
            int i1 = 0x7fffffff;
            if (lane < 16) { m1 = cv[64 + lane]; i1 = ci[64 + lane]; }
            for (int it = 0; it < TOPK; ++it) {
                float bv = m0; int bidx = i0;
                if (m1 > bv || (m1 == bv && i1 < bidx)) { bv = m1; bidx = i1; }
#pragma unroll
                for (int m = 32; m >= 1; m >>= 1) {
                    float ov = __shfl_xor(bv, m, 64);
                    int oi = __shfl_xor(bidx, m, 64);
                    if (ov > bv || (ov == bv && oi < bidx)) { bv = ov; bidx = oi; }
                }
                if (lane == 0) tk[row * TOPK + it] = bidx;
                if (i0 == bidx) m0 = -3.0e38f;
                if (i1 == bidx) m1 = -3.0e38f;
            }
        }
        return;
    }

    if (bid < GT_BLKS + HS_BLKS) {
        // ---- hscal: h = x@W_lin (bf16) + fully-folded per-node att scalars ----
        const int base = (bid - GT_BLKS) * 16 + w * 4;
        float wl[F_IN];
#pragma unroll
        for (int f = 0; f < F_IN; ++f) wl[f] = W_lin[f * DIM + lane];
        const float ai = att_i[lane], aj = att_j[lane];
        const float aei = att_em_i[lane], aej = att_em_j[lane];
#pragma unroll
        for (int r = 0; r < 4; ++r) {
            const int node = base + r;
            const int i = node & (N_NODES - 1);
            const float ev = emb[i * DIM + lane];
            const float* dp = data + node * F_IN;
            float hv = 0.f;
#pragma unroll
            for (int f = 0; f < F_IN; ++f) hv = fmaf(dp[f], wl[f], hv);
            h[node * DIM + lane] = __float2bfloat16(hv);
            float s1 = fmaf(hv, ai, ev * aei);
            float s2 = fmaf(hv, aj, ev * aej);
#pragma unroll
            for (int m = 32; m >= 1; m >>= 1) {
                s1 += __shfl_xor(s1, m, 64);
                s2 += __shfl_xor(s2, m, 64);
            }
            if (lane == 0) { ddt[node] = s1; sst[node] = s2; }
        }
        return;
    }

    // ---- bnp fold ----
    if (t < DIM) {
        float a1 = g1[t] * rsqrtf(v1[t] + 1e-5f);
        float c1 = (gnn_bias[t] - m1[t]) * a1 + b1[t];
        float a2 = g2[t] * rsqrtf(v2[t] + 1e-5f);
        float c2 = b2[t] - m2[t] * a2;
        bnp[t] = make_float4(a1, c1, a2, c2);
    }
}

// ---- K2: softmax + aggregate + folded BN/head (bf16 h rows, SGPR addressing) ----
__global__ __launch_bounds__(256) void k_main(
    const __hip_bfloat16* __restrict__ h, const float* __restrict__ emb,
    const float* __restrict__ ddt, const float* __restrict__ sst,
    const int* __restrict__ tk, const float4* __restrict__ bnp,
    const float* __restrict__ outW, const float* __restrict__ outB,
    float* __restrict__ out) {
    const int bid = blockIdx.x;
    const int nb = (bid & 7) * 2048 + (bid >> 3);   // XCD swizzle
    const int w = threadIdx.x >> 6, lane = threadIdx.x & 63;
    const int node = nb * 4 + w;
    const int i = node & (N_NODES - 1);
    const int bbase = node & ~(N_NODES - 1);

    int j = i;
    if (lane < TOPK) j = tk[i * TOPK + lane];

    float sv = 0.f;
    if (lane <= TOPK) sv = sst[bbase + j];
    const float ddv = ddt[node];

    const __hip_bfloat16* hb = h + (size_t)bbase * DIM + lane;
    float hvf[TOPK + 1];
#pragma unroll
    for (int k = 0; k < TOPK; ++k) {
        int jk = __builtin_amdgcn_readlane(j, k);
        hvf[k] = __bfloat162float(hb[(size_t)jk * DIM]);
    }
    hvf[TOPK] = __bfloat162float(hb[(size_t)i * DIM]);

    const bool masked = (lane < TOPK) && (j == i);
    float lg = -3.0e38f;
    if (lane <= TOPK) {
        float l = ddv + sv;
        l = (l > 0.f) ? l : 0.2f * l;              // leaky_relu(0.2)
        lg = masked ? -3.0e38f : l;
    }
    float m = lg;
#pragma unroll
    for (int mm = 16; mm >= 1; mm >>= 1) m = fmaxf(m, __shfl_xor(m, mm, 64));
    float ex = (lane <= TOPK && !masked) ? __expf(lg - m) : 0.f;
    float s = ex;
#pragma unroll
    for (int mm = 16; mm >= 1; mm >>= 1) s += __shfl_xor(s, mm, 64);
    const float alpha = ex / s;

    float agg = 0.f;
#pragma unroll
    for (int k = 0; k <= TOPK; ++k) {
        int ab = __builtin_amdgcn_readlane(__float_as_int(alpha), k);
        agg = fmaf(__int_as_float(ab), hvf[k], agg);
    }

    const float4 p = bnp[lane];
    float x1 = fmaxf(fmaf(agg, p.x, p.y), 0.f);
    float y = x1 * emb[i * DIM + lane];
    float x2 = fmaxf(fmaf(y, p.z, p.w), 0.f);
    float o = x2 * outW[lane];
#pragma unroll
    for (int mm = 32; mm >= 1; mm >>= 1) o += __shfl_xor(o, mm, 64);
    if (lane == 0) out[node] = o + outB[0];
}

extern "C" void kernel_launch(void* const* d_in, const int* in_sizes, int n_in,
                              void* d_out, int out_size, void* d_ws, size_t ws_size,
                              hipStream_t stream) {
    const float* data     = (const float*)d_in[0];
    const float* emb      = (const float*)d_in[1];
    const float* W_lin    = (const float*)d_in[2];
    const float* att_i    = (const float*)d_in[3];
    const float* att_j    = (const float*)d_in[4];
    const float* att_em_i = (const float*)d_in[5];
    const float* att_em_j = (const float*)d_in[6];
    const float* gnn_bias = (const float*)d_in[7];
    const float* g1 = (const float*)d_in[8];
    const float* b1 = (const float*)d_in[9];
    const float* m1 = (const float*)d_in[10];
    const float* v1 = (const float*)d_in[11];
    const float* g2 = (const float*)d_in[12];
    const float* b2 = (const float*)d_in[13];
    const float* m2 = (const float*)d_in[14];
    const float* v2 = (const float*)d_in[15];
    const float* outW = (const float*)d_in[16];
    const float* outB = (const float*)d_in[17];
    float* out = (float*)d_out;

    char* ws = (char*)d_ws;
    __hip_bfloat16* h = (__hip_bfloat16*)ws;                      // 8 MB
    float* ddt  = (float*)(ws + ((size_t)8 << 20));               // 256 KB
    float* sst  = ddt + BN_TOT;                                   // 256 KB
    int*   tk   = (int*)(sst + BN_TOT);                           // 80 KB
    float4* bnp = (float4*)(tk + N_NODES * TOPK);                 // 1 KB

    k_build<<<K1_BLKS, 256, 0, stream>>>(
        data, emb, W_lin, att_i, att_j, att_em_i, att_em_j, gnn_bias,
        g1, b1, m1, v1, g2, b2, m2, v2,
        h, ddt, sst, tk, bnp);
    k_main<<<BN_TOT / 4, 256, 0, stream>>>(h, emb, ddt, sst, tk, bnp,
                                           outW, outB, out);
}

// Round 13
// 78.189 us; speedup vs baseline: 1.4098x; 1.4098x over previous
//
#include <hip/hip_runtime.h>
#include <hip/hip_bf16.h>

#define N_NODES 1024
#define B_SZ 64
#define F_IN 10
#define DIM 64
#define TOPK 20
#define BN_TOT (B_SZ * N_NODES)   // 65536

#define PREP_BLKS 256             // rn: 4 nodes/block
#define HS_BLKS 4096              // hscal: 16 nodes/block
#define K0_BLKS (PREP_BLKS + 1 + HS_BLKS)

// ---- K0 (k_pre): rn + bnp fold + hscal (bf16 h, folded scalars) ----
__global__ __launch_bounds__(256) void k_pre(
    const float* __restrict__ data, const float* __restrict__ emb,
    const float* __restrict__ W_lin,
    const float* __restrict__ att_i, const float* __restrict__ att_j,
    const float* __restrict__ att_em_i, const float* __restrict__ att_em_j,
    const float* __restrict__ gnn_bias,
    const float* __restrict__ g1, const float* __restrict__ b1,
    const float* __restrict__ m1, const float* __restrict__ v1,
    const float* __restrict__ g2, const float* __restrict__ b2,
    const float* __restrict__ m2, const float* __restrict__ v2,
    float* __restrict__ rn, __hip_bfloat16* __restrict__ h,
    float* __restrict__ ddt, float* __restrict__ sst, float4* __restrict__ bnp) {
    const int bid = blockIdx.x;
    const int t = threadIdx.x;
    const int lane = t & 63, w = t >> 6;

    if (bid < PREP_BLKS) {
        const int node = bid * 4 + w;
        float e = emb[node * DIM + lane];
        float t3 = e * e;
#pragma unroll
        for (int m = 32; m >= 1; m >>= 1) t3 += __shfl_xor(t3, m, 64);
        if (lane == 0) rn[node] = rsqrtf(t3);
        return;
    }
    if (bid == PREP_BLKS) {
        if (t < DIM) {
            float a1 = g1[t] * rsqrtf(v1[t] + 1e-5f);
            float c1 = (gnn_bias[t] - m1[t]) * a1 + b1[t];
            float a2 = g2[t] * rsqrtf(v2[t] + 1e-5f);
            float c2 = b2[t] - m2[t] * a2;
            bnp[t] = make_float4(a1, c1, a2, c2);
        }
        return;
    }
    // hscal
    {
        const int base = (bid - PREP_BLKS - 1) * 16 + w * 4;
        float wl[F_IN];
#pragma unroll
        for (int f = 0; f < F_IN; ++f) wl[f] = W_lin[f * DIM + lane];
        const float ai = att_i[lane], aj = att_j[lane];
        const float aei = att_em_i[lane], aej = att_em_j[lane];
#pragma unroll
        for (int r = 0; r < 4; ++r) {
            const int node = base + r;
            const int i = node & (N_NODES - 1);
            const float ev = emb[i * DIM + lane];
            const float* dp = data + node * F_IN;
            float hv = 0.f;
#pragma unroll
            for (int f = 0; f < F_IN; ++f) hv = fmaf(dp[f], wl[f], hv);
            h[node * DIM + lane] = __float2bfloat16(hv);
            float s1 = fmaf(hv, ai, ev * aei);
            float s2 = fmaf(hv, aj, ev * aej);
#pragma unroll
            for (int m = 32; m >= 1; m >>= 1) {
                s1 += __shfl_xor(s1, m, 64);
                s2 += __shfl_xor(s2, m, 64);
            }
            if (lane == 0) { ddt[node] = s1; sst[node] = s2; }
        }
    }
}

// ---- K1 (k_gemm): normalized cos = (emb@embT) * rn_i * rn_j, 64x64 tiles ----
__global__ __launch_bounds__(256) void k_gemm(const float* __restrict__ emb,
                                              const float* __restrict__ rn,
                                              float* __restrict__ cosm) {
    __shared__ float As[64][65];
    __shared__ float Bs[64][65];
    __shared__ float rA[64], rB[64];
    const int r0 = (blockIdx.x >> 4) * 64, c0 = (blockIdx.x & 15) * 64;
    const int t = threadIdx.x;
#pragma unroll
    for (int k = 0; k < 16; ++k) {
        int idx = t + k * 256;
        int rr = idx >> 6, cc = idx & 63;
        As[rr][cc] = emb[(r0 + rr) * DIM + cc];
        Bs[rr][cc] = emb[(c0 + rr) * DIM + cc];
    }
    if (t < 64) { rA[t] = rn[r0 + t]; rB[t] = rn[c0 + t]; }
    __syncthreads();
    const int tx = t & 15, ty = t >> 4;
    float acc[4][4] = {};
#pragma unroll 8
    for (int d = 0; d < 64; ++d) {
        float a[4], b[4];
#pragma unroll
        for (int ii = 0; ii < 4; ++ii) a[ii] = As[ty * 4 + ii][d];
#pragma unroll
        for (int jj = 0; jj < 4; ++jj) b[jj] = Bs[tx * 4 + jj][d];
#pragma unroll
        for (int ii = 0; ii < 4; ++ii)
#pragma unroll
            for (int jj = 0; jj < 4; ++jj) acc[ii][jj] += a[ii] * b[jj];
    }
    float rb0 = rB[tx * 4 + 0], rb1 = rB[tx * 4 + 1];
    float rb2 = rB[tx * 4 + 2], rb3 = rB[tx * 4 + 3];
#pragma unroll
    for (int ii = 0; ii < 4; ++ii) {
        float ra = rA[ty * 4 + ii];
        float4 o = make_float4(acc[ii][0] * ra * rb0, acc[ii][1] * ra * rb1,
                               acc[ii][2] * ra * rb2, acc[ii][3] * ra * rb3);
        *(float4*)&cosm[(size_t)(r0 + ty * 4 + ii) * N_NODES + c0 + tx * 4] = o;
    }
}

// ---- K2 (k_topk): pure selection from normalized cos row ----
__global__ __launch_bounds__(256) void k_topk(const float* __restrict__ cosm,
                                              int* __restrict__ tk) {
    __shared__ float cv[4 * TOPK];
    __shared__ int ci[4 * TOPK];
    const int row = blockIdx.x;
    const int t = threadIdx.x;
    const int w = t >> 6, lane = t & 63;
    const int j0 = t * 4;

    float4 g4 = ((const float4*)(cosm + (size_t)row * N_NODES))[t];
    float v0 = g4.x, v1 = g4.y, v2 = g4.z, v3 = g4.w;

    // phase 1: per-wave exact top-20 of its 256 cols (static regs only)
    for (int it = 0; it < TOPK; ++it) {
        float bv = v0; int bq = 0;
        if (v1 > bv) { bv = v1; bq = 1; }
        if (v2 > bv) { bv = v2; bq = 2; }
        if (v3 > bv) { bv = v3; bq = 3; }
        int bidx = j0 + bq;
#pragma unroll
        for (int m = 32; m >= 1; m >>= 1) {
            float ov = __shfl_xor(bv, m, 64);
            int oi = __shfl_xor(bidx, m, 64);
            if (ov > bv || (ov == bv && oi < bidx)) { bv = ov; bidx = oi; }
        }
        if (lane == 0) { cv[w * TOPK + it] = bv; ci[w * TOPK + it] = bidx; }
        v0 = (j0 + 0 == bidx) ? -3.0e38f : v0;
        v1 = (j0 + 1 == bidx) ? -3.0e38f : v1;
        v2 = (j0 + 2 == bidx) ? -3.0e38f : v2;
        v3 = (j0 + 3 == bidx) ? -3.0e38f : v3;
    }
    __syncthreads();

    // phase 2: wave 0 merges 80 candidates -> top-20
    if (w == 0) {
        float m0 = cv[lane];
        int i0 = ci[lane];
        float m1 = -3.0e38f;
        int i1 = 0x7fffffff;
        if (lane < 16) { m1 = cv[64 + lane]; i1 = ci[64 + lane]; }
        for (int it = 0; it < TOPK; ++it) {
            float bv = m0; int bidx = i0;
            if (m1 > bv || (m1 == bv && i1 < bidx)) { bv = m1; bidx = i1; }
#pragma unroll
            for (int m = 32; m >= 1; m >>= 1) {
                float ov = __shfl_xor(bv, m, 64);
                int oi = __shfl_xor(bidx, m, 64);
                if (ov > bv || (ov == bv && oi < bidx)) { bv = ov; bidx = oi; }
            }
            if (lane == 0) tk[row * TOPK + it] = bidx;
            if (i0 == bidx) m0 = -3.0e38f;
            if (i1 == bidx) m1 = -3.0e38f;
        }
    }
}

// ---- K3 (k_main): softmax + aggregate + folded BN/head ----
__global__ __launch_bounds__(256) void k_main(
    const __hip_bfloat16* __restrict__ h, const float* __restrict__ emb,
    const float* __restrict__ ddt, const float* __restrict__ sst,
    const int* __restrict__ tk, const float4* __restrict__ bnp,
    const float* __restrict__ outW, const float* __restrict__ outB,
    float* __restrict__ out) {
    const int bid = blockIdx.x;
    const int nb = (bid & 7) * 2048 + (bid >> 3);   // XCD swizzle
    const int w = threadIdx.x >> 6, lane = threadIdx.x & 63;
    const int node = nb * 4 + w;
    const int i = node & (N_NODES - 1);
    const int bbase = node & ~(N_NODES - 1);

    int j = i;
    if (lane < TOPK) j = tk[i * TOPK + lane];

    float sv = 0.f;
    if (lane <= TOPK) sv = sst[bbase + j];
    const float ddv = ddt[node];

    const __hip_bfloat16* hb = h + (size_t)bbase * DIM + lane;
    float hvf[TOPK + 1];
#pragma unroll
    for (int k = 0; k < TOPK; ++k) {
        int jk = __builtin_amdgcn_readlane(j, k);
        hvf[k] = __bfloat162float(hb[(size_t)jk * DIM]);
    }
    hvf[TOPK] = __bfloat162float(hb[(size_t)i * DIM]);

    const bool masked = (lane < TOPK) && (j == i);
    float lg = -3.0e38f;
    if (lane <= TOPK) {
        float l = ddv + sv;
        l = (l > 0.f) ? l : 0.2f * l;              // leaky_relu(0.2)
        lg = masked ? -3.0e38f : l;
    }
    float m = lg;
#pragma unroll
    for (int mm = 16; mm >= 1; mm >>= 1) m = fmaxf(m, __shfl_xor(m, mm, 64));
    float ex = (lane <= TOPK && !masked) ? __expf(lg - m) : 0.f;
    float s = ex;
#pragma unroll
    for (int mm = 16; mm >= 1; mm >>= 1) s += __shfl_xor(s, mm, 64);
    const float alpha = ex / s;

    float agg = 0.f;
#pragma unroll
    for (int k = 0; k <= TOPK; ++k) {
        int ab = __builtin_amdgcn_readlane(__float_as_int(alpha), k);
        agg = fmaf(__int_as_float(ab), hvf[k], agg);
    }

    const float4 p = bnp[lane];
    float x1 = fmaxf(fmaf(agg, p.x, p.y), 0.f);
    float y = x1 * emb[i * DIM + lane];
    float x2 = fmaxf(fmaf(y, p.z, p.w), 0.f);
    float o = x2 * outW[lane];
#pragma unroll
    for (int mm = 32; mm >= 1; mm >>= 1) o += __shfl_xor(o, mm, 64);
    if (lane == 0) out[node] = o + outB[0];
}

extern "C" void kernel_launch(void* const* d_in, const int* in_sizes, int n_in,
                              void* d_out, int out_size, void* d_ws, size_t ws_size,
                              hipStream_t stream) {
    const float* data     = (const float*)d_in[0];
    const float* emb      = (const float*)d_in[1];
    const float* W_lin    = (const float*)d_in[2];
    const float* att_i    = (const float*)d_in[3];
    const float* att_j    = (const float*)d_in[4];
    const float* att_em_i = (const float*)d_in[5];
    const float* att_em_j = (const float*)d_in[6];
    const float* gnn_bias = (const float*)d_in[7];
    const float* g1 = (const float*)d_in[8];
    const float* b1 = (const float*)d_in[9];
    const float* m1 = (const float*)d_in[10];
    const float* v1 = (const float*)d_in[11];
    const float* g2 = (const float*)d_in[12];
    const float* b2 = (const float*)d_in[13];
    const float* m2 = (const float*)d_in[14];
    const float* v2 = (const float*)d_in[15];
    const float* outW = (const float*)d_in[16];
    const float* outB = (const float*)d_in[17];
    float* out = (float*)d_out;

    char* ws = (char*)d_ws;
    __hip_bfloat16* h = (__hip_bfloat16*)ws;                      // 8 MB
    float* cosm = (float*)(ws + ((size_t)8 << 20));               // 4 MB
    float* ddt  = (float*)(ws + ((size_t)12 << 20));              // 256 KB
    float* sst  = ddt + BN_TOT;                                   // 256 KB
    float* rn   = sst + BN_TOT;                                   // 4 KB
    int*   tk   = (int*)(rn + N_NODES);                           // 80 KB
    float4* bnp = (float4*)(tk + N_NODES * TOPK);                 // 1 KB

    k_pre<<<K0_BLKS, 256, 0, stream>>>(
        data, emb, W_lin, att_i, att_j, att_em_i, att_em_j, gnn_bias,
        g1, b1, m1, v1, g2, b2, m2, v2,
        rn, h, ddt, sst, bnp);
    k_gemm<<<256, 256, 0, stream>>>(emb, rn, cosm);
    k_topk<<<N_NODES, 256, 0, stream>>>(cosm, tk);
    k_main<<<BN_TOT / 4, 256, 0, stream>>>(h, emb, ddt, sst, tk, bnp,
                                           outW, outB, out);
}